// Round 1
// baseline (232.407 us; speedup 1.0000x reference)
//
#include <hip/hip_runtime.h>

// Deformable conv, B=4 C=64 H=W=128 O=64 K=3x3 stride=1 pad=1 dil=1 DG=1.
// Implicit GEMM: M=O=64, K=C*9=576, N=B*HO*WO=65536.
// v1: fp32 VALU MAC, fused sampling, one block per output row.

#define B_  4
#define C_  64
#define H_  128
#define W_  128
#define O_  64
#define K_  9
#define HO_ 128
#define WO_ 128
#define CK_ (C_ * K_)   // 576

// Transpose weight [O][C*9] -> [C*9][O] so per-channel chunks are contiguous
// and the main kernel can stage them coalesced.
__global__ void wt_transpose_kernel(const float* __restrict__ w,
                                    float* __restrict__ wt) {
    int t = blockIdx.x * 256 + threadIdx.x;
    if (t < O_ * CK_) {
        int o  = t / CK_;
        int ck = t - o * CK_;
        wt[ck * O_ + o] = w[t];
    }
}

__global__ __launch_bounds__(256)
void dcn_kernel(const float* __restrict__ x, const float* __restrict__ off,
                const float* __restrict__ wt, const float* __restrict__ bias,
                float* __restrict__ out) {
    __shared__ float sS[K_ * WO_];   // sampled values, 9 x 128 = 4.5 KB
    __shared__ float sW[K_ * O_];    // weight chunk,  9 x 64  = 2.25 KB

    const int tid = threadIdx.x;
    const int bid = blockIdx.x;          // 0..511
    const int ho  = bid & (HO_ - 1);
    const int b   = bid >> 7;

    // ---- per-thread bilinear metadata, kept in registers ----
    // samples s = k*128 + wo, s in [0,1152); thread owns s = tid + r*256
    int   midx[5][4];
    float mwt[5][4];
#pragma unroll
    for (int r = 0; r < 5; ++r) {
        int s = tid + r * 256;
        if (s >= K_ * WO_) {
#pragma unroll
            for (int q = 0; q < 4; ++q) { midx[r][q] = 0; mwt[r][q] = 0.f; }
            continue;
        }
        int k  = s >> 7;         // tap index 0..8
        int wo = s & (WO_ - 1);
        int ki = k / 3;
        int kj = k - ki * 3;
        float oy = off[(((b * 18) + 2 * k    ) * HO_ + ho) * WO_ + wo];
        float ox = off[(((b * 18) + 2 * k + 1) * HO_ + ho) * WO_ + wo];
        float py = (float)(ho - 1 + ki) + oy;
        float px = (float)(wo - 1 + kj) + ox;
        float y0f = floorf(py), x0f = floorf(px);
        int   y0 = (int)y0f,   x0 = (int)x0f;
        float ly = py - y0f,   lx = px - x0f;
        float hy = 1.f - ly,   hx = 1.f - lx;
        int y1 = y0 + 1, x1 = x0 + 1;
        float vy0 = (y0 >= 0 && y0 < H_) ? 1.f : 0.f;
        float vy1 = (y1 >= 0 && y1 < H_) ? 1.f : 0.f;
        float vx0 = (x0 >= 0 && x0 < W_) ? 1.f : 0.f;
        float vx1 = (x1 >= 0 && x1 < W_) ? 1.f : 0.f;
        int cy0 = min(max(y0, 0), H_ - 1), cy1 = min(max(y1, 0), H_ - 1);
        int cx0 = min(max(x0, 0), W_ - 1), cx1 = min(max(x1, 0), W_ - 1);
        midx[r][0] = cy0 * W_ + cx0;  mwt[r][0] = hy * hx * vy0 * vx0;
        midx[r][1] = cy0 * W_ + cx1;  mwt[r][1] = hy * lx * vy0 * vx1;
        midx[r][2] = cy1 * W_ + cx0;  mwt[r][2] = ly * hx * vy1 * vx0;
        midx[r][3] = cy1 * W_ + cx1;  mwt[r][3] = ly * lx * vy1 * vx1;
    }

    // ---- MAC thread tile: 4 output channels x 8 positions ----
    const int to = tid >> 4;        // 0..15
    const int tn = tid & 15;        // 0..15
    const int o0 = to * 4;
    const int n0 = tn * 8;

    float acc[4][8];
#pragma unroll
    for (int i = 0; i < 4; ++i)
#pragma unroll
        for (int j = 0; j < 8; ++j) acc[i][j] = 0.f;

    const float* xb = x + (size_t)b * C_ * H_ * W_;

    for (int c = 0; c < C_; ++c) {
        // stage weight chunk (576 floats, contiguous in wt) coalesced
        if (tid < 144) {
            ((float4*)sW)[tid] = ((const float4*)(wt + c * (K_ * O_)))[tid];
        }
        // cooperative bilinear sampling for this channel
        const float* xc = xb + c * (H_ * W_);
#pragma unroll
        for (int r = 0; r < 5; ++r) {
            int s = tid + r * 256;
            if (s < K_ * WO_) {
                sS[s] = mwt[r][0] * xc[midx[r][0]]
                      + mwt[r][1] * xc[midx[r][1]]
                      + mwt[r][2] * xc[midx[r][2]]
                      + mwt[r][3] * xc[midx[r][3]];
            }
        }
        __syncthreads();
#pragma unroll
        for (int k = 0; k < K_; ++k) {
            const float4 wv = *(const float4*)&sW[k * O_ + o0];
            const float4 s0 = *(const float4*)&sS[k * WO_ + n0];
            const float4 s1 = *(const float4*)&sS[k * WO_ + n0 + 4];
            const float wa[4] = {wv.x, wv.y, wv.z, wv.w};
            const float sa[8] = {s0.x, s0.y, s0.z, s0.w, s1.x, s1.y, s1.z, s1.w};
#pragma unroll
            for (int i = 0; i < 4; ++i)
#pragma unroll
                for (int j = 0; j < 8; ++j)
                    acc[i][j] = fmaf(wa[i], sa[j], acc[i][j]);
        }
        __syncthreads();
    }

    // ---- epilogue: bias + coalesced float4 stores ----
#pragma unroll
    for (int i = 0; i < 4; ++i) {
        const int o = o0 + i;
        const float bv = bias[o];
        float* op = out + (((size_t)b * O_ + o) * HO_ + ho) * WO_ + n0;
        float4 v0, v1;
        v0.x = acc[i][0] + bv; v0.y = acc[i][1] + bv;
        v0.z = acc[i][2] + bv; v0.w = acc[i][3] + bv;
        v1.x = acc[i][4] + bv; v1.y = acc[i][5] + bv;
        v1.z = acc[i][6] + bv; v1.w = acc[i][7] + bv;
        *(float4*)op       = v0;
        *(float4*)(op + 4) = v1;
    }
}

extern "C" void kernel_launch(void* const* d_in, const int* in_sizes, int n_in,
                              void* d_out, int out_size, void* d_ws, size_t ws_size,
                              hipStream_t stream) {
    const float* x    = (const float*)d_in[0];
    const float* off  = (const float*)d_in[1];
    const float* w    = (const float*)d_in[2];
    const float* bias = (const float*)d_in[3];
    float* out = (float*)d_out;
    float* wt  = (float*)d_ws;   // 576*64 floats = 147456 B

    hipLaunchKernelGGL(wt_transpose_kernel, dim3(144), dim3(256), 0, stream, w, wt);
    hipLaunchKernelGGL(dcn_kernel, dim3(B_ * HO_), dim3(256), 0, stream,
                       x, off, wt, bias, out);
}

// Round 2
// 167.653 us; speedup vs baseline: 1.3862x; 1.3862x over previous
//
#include <hip/hip_runtime.h>

// Deformable conv B=4 C=64 H=W=128 O=64 3x3 s1 p1 d1, DG=1.
// v2: fused bilinear sampling + bf16 hi/lo 3-term MFMA implicit GEMM.
// K3 index = (t, k, c): t in {0,1,2} -> (sh*wh, sl*wh, sh*wl); inner dim = channel octet
// so sampling writes and B-fragment reads are contiguous 16B (conflict-free).

#define B_  4
#define C_  64
#define H_  128
#define W_  128
#define O_  64
#define HO_ 128
#define WO_ 128
#define NCH 8            // channels per chunk (K-octet inner dim)
#define NCHUNK 8         // C / NCH
#define NG  28           // K-groups of 8 per chunk: 27 real (3 terms x 9 taps) + 1 zero pad
#define KSTEPS 7         // NG*8 / 32
#define NTASK (9 * WO_)  // sampling tasks per chunk: (tap k, wo)

typedef __attribute__((ext_vector_type(8))) short short8;   // 8 bf16 = 4 VGPRs (MFMA A/B frag)
typedef __attribute__((ext_vector_type(4))) float f32x4;    // MFMA C/D frag

__device__ __forceinline__ unsigned short f2bf(float f) {   // RNE fp32->bf16
    unsigned int u = __builtin_bit_cast(unsigned int, f);
    return (unsigned short)((u + 0x7FFFu + ((u >> 16) & 1u)) >> 16);
}
__device__ __forceinline__ float bf2f(unsigned short h) {
    unsigned int u = ((unsigned int)h) << 16;
    return __builtin_bit_cast(float, u);
}

// Weight transform: wt3[((ch*NG + g)*64 + o)*8 + e], g=(t*9+k) real for g<27, pad zeros at g=27.
// value = (t==2) ? bf16_lo(w[o][ch*8+e][k]) : bf16_hi(w[o][ch*8+e][k])
__global__ __launch_bounds__(256)
void wt3_prep(const float* __restrict__ w, unsigned short* __restrict__ wt3) {
    int t = blockIdx.x * 256 + threadIdx.x;
    if (t >= NCHUNK * NG * O_) return;
    int o  = t & 63;
    int g  = (t >> 6) % NG;
    int ch = (t >> 6) / NG;
    union { unsigned short u[8]; short8 v; } pk;
    if (g >= 27) {
#pragma unroll
        for (int e = 0; e < 8; ++e) pk.u[e] = 0;
    } else {
        int t3 = g / 9, k = g - 9 * t3;
#pragma unroll
        for (int e = 0; e < 8; ++e) {
            int c = ch * NCH + e;
            float wf = w[(o * C_ + c) * 9 + k];
            unsigned short wh = f2bf(wf);
            pk.u[e] = (t3 == 2) ? f2bf(wf - bf2f(wh)) : wh;
        }
    }
    *(short8*)(wt3 + (size_t)t * 8) = pk.v;
}

__global__ __launch_bounds__(256)
void dcn_mfma(const float* __restrict__ x, const float* __restrict__ off,
              const unsigned short* __restrict__ wt3, const float* __restrict__ bias,
              float* __restrict__ out) {
    // S staging: [g][wo][e] bf16, g in [0,28), e = channel octet index. 56 KB.
    __shared__ unsigned short sS[NG * WO_ * 8];

    const int tid = threadIdx.x;
    const int bid = blockIdx.x;          // (b, ho)
    const int ho  = bid & (HO_ - 1);
    const int b   = bid >> 7;

    // ---- bilinear metadata per (k,wo) task, computed ONCE (c-invariant), kept in regs ----
    int   a0_[5], a1_[5];          // element index of [cy, ax] rows y0/y1 (ax = clamp(x0,0,126))
    int   sel0_[5], sel1_[5];      // take .y (ax+1) instead of .x (ax) for cx0 / cx1
    float w00_[5], w01_[5], w10_[5], w11_[5];
#pragma unroll
    for (int r = 0; r < 5; ++r) {
        int task = tid + r * 256;
        int tk = (task < NTASK) ? task : 0;
        int k  = tk >> 7;
        int wo = tk & (WO_ - 1);
        int ki = k / 3, kj = k - 3 * ki;
        float oy = off[(((b * 18) + 2 * k    ) * HO_ + ho) * WO_ + wo];
        float ox = off[(((b * 18) + 2 * k + 1) * HO_ + ho) * WO_ + wo];
        float py = (float)(ho - 1 + ki) + oy;
        float px = (float)(wo - 1 + kj) + ox;
        float y0f = floorf(py), x0f = floorf(px);
        int   y0 = (int)y0f,   x0 = (int)x0f;
        float ly = py - y0f,   lx = px - x0f;
        float hy = 1.f - ly,   hx = 1.f - lx;
        int y1 = y0 + 1, x1 = x0 + 1;
        float vy0 = (y0 >= 0 && y0 < H_) ? 1.f : 0.f;
        float vy1 = (y1 >= 0 && y1 < H_) ? 1.f : 0.f;
        float vx0 = (x0 >= 0 && x0 < W_) ? 1.f : 0.f;
        float vx1 = (x1 >= 0 && x1 < W_) ? 1.f : 0.f;
        int cy0 = min(max(y0, 0), H_ - 1), cy1 = min(max(y1, 0), H_ - 1);
        int cx0 = min(max(x0, 0), W_ - 1), cx1 = min(max(x1, 0), W_ - 1);
        int ax  = min(max(x0, 0), W_ - 2);
        a0_[r] = cy0 * W_ + ax;
        a1_[r] = cy1 * W_ + ax;
        sel0_[r] = (cx0 != ax);
        sel1_[r] = (cx1 != ax);
        w00_[r] = hy * hx * vy0 * vx0;
        w01_[r] = hy * lx * vy0 * vx1;
        w10_[r] = ly * hx * vy1 * vx0;
        w11_[r] = ly * lx * vy1 * vx1;
    }

    // zero the pad K-group (g=27) once; read every chunk, never rewritten
    {
        unsigned int* p = (unsigned int*)&sS[27 * WO_ * 8];
        p[tid] = 0u; p[tid + 256] = 0u;
    }

    // ---- GEMM lane mapping ----
    const int lane = tid & 63;
    const int wv   = tid >> 6;        // wave 0..3 -> wo slice of 32
    const int quad = lane >> 4;       // K sub-group within a step
    const int l15  = lane & 15;

    f32x4 acc[4][2];
#pragma unroll
    for (int ot = 0; ot < 4; ++ot)
#pragma unroll
        for (int nt = 0; nt < 2; ++nt)
            acc[ot][nt] = (f32x4){0.f, 0.f, 0.f, 0.f};

    for (int ch = 0; ch < NCHUNK; ++ch) {
        // ---- sample & stage S for this channel octet ----
        const float* xb = x + ((size_t)(b * C_ + ch * NCH)) * (H_ * W_);
#pragma unroll
        for (int r = 0; r < 5; ++r) {
            int task = tid + r * 256;
            if (task < NTASK) {
                int k  = task >> 7;
                int wo = task & (WO_ - 1);
                const int   a0 = a0_[r], a1 = a1_[r];
                const int   s0 = sel0_[r], s1 = sel1_[r];
                const float w00 = w00_[r], w01 = w01_[r], w10 = w10_[r], w11 = w11_[r];
                union { unsigned short u[8]; short8 v; } ph, pl;
#pragma unroll
                for (int e = 0; e < 8; ++e) {
                    const float* xc = xb + e * (H_ * W_);
                    float r0x = xc[a0], r0y = xc[a0 + 1];
                    float r1x = xc[a1], r1y = xc[a1 + 1];
                    float v00 = s0 ? r0y : r0x;
                    float v01 = s1 ? r0y : r0x;
                    float v10 = s0 ? r1y : r1x;
                    float v11 = s1 ? r1y : r1x;
                    float s = w00 * v00 + w01 * v01 + w10 * v10 + w11 * v11;
                    unsigned short h = f2bf(s);
                    ph.u[e] = h;
                    pl.u[e] = f2bf(s - bf2f(h));
                }
                *(short8*)&sS[((     k) * WO_ + wo) * 8] = ph.v;   // t=0: sh
                *(short8*)&sS[(( 9 + k) * WO_ + wo) * 8] = pl.v;   // t=1: sl
                *(short8*)&sS[((18 + k) * WO_ + wo) * 8] = ph.v;   // t=2: sh (pairs with wl)
            }
        }
        __syncthreads();

        // ---- MFMA over this chunk: 7 K-steps of 32 ----
        const unsigned short* wc = wt3 + (size_t)(ch * NG) * O_ * 8;
#pragma unroll
        for (int ks = 0; ks < KSTEPS; ++ks) {
            int g = ks * 4 + quad;
            short8 afr[4], bfr[2];
#pragma unroll
            for (int ot = 0; ot < 4; ++ot)
                afr[ot] = *(const short8*)(wc + (size_t)(g * O_ + ot * 16 + l15) * 8);
#pragma unroll
            for (int nt = 0; nt < 2; ++nt)
                bfr[nt] = *(const short8*)&sS[((g) * WO_ + wv * 32 + nt * 16 + l15) * 8];
#pragma unroll
            for (int ot = 0; ot < 4; ++ot)
#pragma unroll
                for (int nt = 0; nt < 2; ++nt)
                    acc[ot][nt] = __builtin_amdgcn_mfma_f32_16x16x32_bf16(
                        afr[ot], bfr[nt], acc[ot][nt], 0, 0, 0);
        }
        __syncthreads();   // before next chunk overwrites sS
    }

    // ---- epilogue: C/D layout col=lane&15 (wo), row=quad*4+reg (o) ----
#pragma unroll
    for (int ot = 0; ot < 4; ++ot) {
#pragma unroll
        for (int rg = 0; rg < 4; ++rg) {
            int o = ot * 16 + quad * 4 + rg;
            float bv = bias[o];
            float* op = out + (((size_t)(b * O_ + o)) * HO_ + ho) * WO_;
#pragma unroll
            for (int nt = 0; nt < 2; ++nt) {
                int wo = wv * 32 + nt * 16 + l15;
                op[wo] = acc[ot][nt][rg] + bv;
            }
        }
    }
}

extern "C" void kernel_launch(void* const* d_in, const int* in_sizes, int n_in,
                              void* d_out, int out_size, void* d_ws, size_t ws_size,
                              hipStream_t stream) {
    const float* x    = (const float*)d_in[0];
    const float* off  = (const float*)d_in[1];
    const float* w    = (const float*)d_in[2];
    const float* bias = (const float*)d_in[3];
    float* out = (float*)d_out;
    unsigned short* wt3 = (unsigned short*)d_ws;   // 8*28*64*8*2B = 229376 B

    hipLaunchKernelGGL(wt3_prep, dim3((NCHUNK * NG * O_ + 255) / 256), dim3(256), 0, stream,
                       w, wt3);
    hipLaunchKernelGGL(dcn_mfma, dim3(B_ * HO_), dim3(256), 0, stream,
                       x, off, wt3, bias, out);
}

// Round 3
// 143.481 us; speedup vs baseline: 1.6198x; 1.1685x over previous
//
#include <hip/hip_runtime.h>

// Deformable conv B=4 C=64 H=W=128 O=64 3x3 s1 p1 d1, DG=1.
// v3: NHWC-octet x layout (contiguous 64B per bilinear corner-pair), bf16 hi/lo
// 3-term MFMA implicit GEMM, LDS dedup (sh stored once), grid 1024 (wo halves).

#define B_  4
#define C_  64
#define H_  128
#define W_  128
#define O_  64
#define HO_ 128
#define WO_ 128
#define NCH 8            // channels per chunk
#define NCHUNK 8         // C / NCH
#define NG  28           // K-groups of 8 per chunk: 27 real (3 terms x 9 taps) + 1 pad
#define KSTEPS 7         // NG*8 / 32
#define NT_ 64           // wo tile per block
#define NTASK (9 * NT_)  // sampling tasks per chunk: (tap k, wo_local) = 576
#define SGRP 19          // LDS S groups: 9 sh + 9 sl + 1 zero pad

typedef __attribute__((ext_vector_type(8))) short short8;
typedef __attribute__((ext_vector_type(4))) float f32x4;

__device__ __forceinline__ unsigned short f2bf(float f) {
    unsigned int u = __builtin_bit_cast(unsigned int, f);
    return (unsigned short)((u + 0x7FFFu + ((u >> 16) & 1u)) >> 16);
}
__device__ __forceinline__ float bf2f(unsigned short h) {
    unsigned int u = ((unsigned int)h) << 16;
    return __builtin_bit_cast(float, u);
}

// x [B][C][H][W] -> xT [B][CH=8][H][W][8]  (channel octets innermost)
__global__ __launch_bounds__(256)
void x_nhwc(const float* __restrict__ x, float* __restrict__ xt) {
    int t = blockIdx.x * 256 + threadIdx.x;     // (b,ch,y,x): 4*8*128*128 = 524288
    if (t >= B_ * NCHUNK * H_ * W_) return;
    int xc = t & 127;
    int y  = (t >> 7) & 127;
    int ch = (t >> 14) & 7;
    int b  = t >> 17;
    float4 v0, v1;
    const float* xp = x + (((size_t)(b * C_ + ch * NCH) * H_) + y) * W_ + xc;
    v0.x = xp[0 * H_ * W_]; v0.y = xp[1 * H_ * W_];
    v0.z = xp[2 * H_ * W_]; v0.w = xp[3 * H_ * W_];
    v1.x = xp[4 * H_ * W_]; v1.y = xp[5 * H_ * W_];
    v1.z = xp[6 * H_ * W_]; v1.w = xp[7 * H_ * W_];
    float4* op = (float4*)(xt + (size_t)t * 8);
    op[0] = v0; op[1] = v1;
}

// wt3[((ch*NG + g)*64 + o)*8 + e]; g = t*9+k for g<27 (t: 0=wh,1=wh,2=wl pairing
// with sh,sl,sh), zeros at g=27.
__global__ __launch_bounds__(256)
void wt3_prep(const float* __restrict__ w, unsigned short* __restrict__ wt3) {
    int t = blockIdx.x * 256 + threadIdx.x;
    if (t >= NCHUNK * NG * O_) return;
    int o  = t & 63;
    int g  = (t >> 6) % NG;
    int ch = (t >> 6) / NG;
    union { unsigned short u[8]; short8 v; } pk;
    if (g >= 27) {
#pragma unroll
        for (int e = 0; e < 8; ++e) pk.u[e] = 0;
    } else {
        int t3 = g / 9, k = g - 9 * t3;
#pragma unroll
        for (int e = 0; e < 8; ++e) {
            int c = ch * NCH + e;
            float wf = w[(o * C_ + c) * 9 + k];
            unsigned short wh = f2bf(wf);
            pk.u[e] = (t3 == 2) ? f2bf(wf - bf2f(wh)) : wh;
        }
    }
    *(short8*)(wt3 + (size_t)t * 8) = pk.v;
}

__global__ __launch_bounds__(256, 4)
void dcn_mfma(const float* __restrict__ xt, const float* __restrict__ off,
              const unsigned short* __restrict__ wt3, const float* __restrict__ bias,
              float* __restrict__ out) {
    // S staging: [g][wo_local][e] bf16; g<9: sh, 9..17: sl, 18: zero pad. 19 KB.
    __shared__ unsigned short sS[SGRP * NT_ * 8];

    const int tid = threadIdx.x;
    const int bid = blockIdx.x;              // (b, ho, wo-half)
    const int w2  = bid & 1;
    const int ho  = (bid >> 1) & (HO_ - 1);
    const int b   = bid >> 8;
    const int woB = w2 * NT_;

    // ---- bilinear metadata per (k, wo_local) task; select folded into weights ----
    int   a0_[3], a1_[3];                    // (y*W + ax) for rows y0/y1, ax=clamp(x0,0,126)
    float ua_[3], ub_[3], va_[3], vb_[3];    // corner weights for cols ax / ax+1
#pragma unroll
    for (int r = 0; r < 3; ++r) {
        int task = tid + r * 256;
        int tk = (task < NTASK) ? task : 0;
        int k  = tk / NT_;
        int wo = (tk - k * NT_) + woB;
        int ki = k / 3, kj = k - 3 * ki;
        float oy = off[(((b * 18) + 2 * k    ) * HO_ + ho) * WO_ + wo];
        float ox = off[(((b * 18) + 2 * k + 1) * HO_ + ho) * WO_ + wo];
        float py = (float)(ho - 1 + ki) + oy;
        float px = (float)(wo - 1 + kj) + ox;
        float y0f = floorf(py), x0f = floorf(px);
        int   y0 = (int)y0f,   x0 = (int)x0f;
        float ly = py - y0f,   lx = px - x0f;
        float hy = 1.f - ly,   hx = 1.f - lx;
        int y1 = y0 + 1, x1 = x0 + 1;
        float vy0 = (y0 >= 0 && y0 < H_) ? 1.f : 0.f;
        float vy1 = (y1 >= 0 && y1 < H_) ? 1.f : 0.f;
        float vx0 = (x0 >= 0 && x0 < W_) ? 1.f : 0.f;
        float vx1 = (x1 >= 0 && x1 < W_) ? 1.f : 0.f;
        int cy0 = min(max(y0, 0), H_ - 1), cy1 = min(max(y1, 0), H_ - 1);
        int cx0 = min(max(x0, 0), W_ - 1), cx1 = min(max(x1, 0), W_ - 1);
        int ax  = min(max(x0, 0), W_ - 2);
        float w00 = hy * hx * vy0 * vx0;     // (y0, cx0)
        float w01 = hy * lx * vy0 * vx1;     // (y0, cx1)
        float w10 = ly * hx * vy1 * vx0;     // (y1, cx0)
        float w11 = ly * lx * vy1 * vx1;     // (y1, cx1)
        float s0 = (cx0 != ax) ? 1.f : 0.f;  // cx0 lands on ax+1
        float s1 = (cx1 != ax) ? 1.f : 0.f;  // cx1 lands on ax+1
        a0_[r] = cy0 * W_ + ax;
        a1_[r] = cy1 * W_ + ax;
        ua_[r] = w00 * (1.f - s0) + w01 * (1.f - s1);
        ub_[r] = w00 * s0 + w01 * s1;
        va_[r] = w10 * (1.f - s0) + w11 * (1.f - s1);
        vb_[r] = w10 * s0 + w11 * s1;
    }

    // zero pad group (g=18): 64*8 ushort = 256 dwords
    ((unsigned int*)&sS[18 * NT_ * 8])[tid] = 0u;

    const int lane = tid & 63;
    const int wv   = tid >> 6;        // wave -> n-slice of 16
    const int quad = lane >> 4;
    const int l15  = lane & 15;

    f32x4 acc[4];
#pragma unroll
    for (int ot = 0; ot < 4; ++ot) acc[ot] = (f32x4){0.f, 0.f, 0.f, 0.f};

    for (int ch = 0; ch < NCHUNK; ++ch) {
        const float4* xc = (const float4*)(xt + ((size_t)(b * NCHUNK + ch)) * (H_ * W_ * 8));
#pragma unroll
        for (int r = 0; r < 3; ++r) {
            int task = tid + r * 256;
            if (task < NTASK) {
                int k  = task / NT_;
                int wo = task - k * NT_;
                const int a0 = a0_[r] * 2, a1 = a1_[r] * 2;
                const float ua = ua_[r], ub = ub_[r], va = va_[r], vb = vb_[r];
                // 64B contiguous per row: (y, ax, c0..7) then (y, ax+1, c0..7)
                float4 p00 = xc[a0], p01 = xc[a0 + 1], p02 = xc[a0 + 2], p03 = xc[a0 + 3];
                float4 p10 = xc[a1], p11 = xc[a1 + 1], p12 = xc[a1 + 2], p13 = xc[a1 + 3];
                const float A0[8] = {p00.x, p00.y, p00.z, p00.w, p01.x, p01.y, p01.z, p01.w};
                const float B0[8] = {p02.x, p02.y, p02.z, p02.w, p03.x, p03.y, p03.z, p03.w};
                const float A1[8] = {p10.x, p10.y, p10.z, p10.w, p11.x, p11.y, p11.z, p11.w};
                const float B1[8] = {p12.x, p12.y, p12.z, p12.w, p13.x, p13.y, p13.z, p13.w};
                union { unsigned short u[8]; short8 v; } ph, pl;
#pragma unroll
                for (int e = 0; e < 8; ++e) {
                    float s = ua * A0[e] + ub * B0[e] + va * A1[e] + vb * B1[e];
                    unsigned short h = f2bf(s);
                    ph.u[e] = h;
                    pl.u[e] = f2bf(s - bf2f(h));
                }
                *(short8*)&sS[((    k) * NT_ + wo) * 8] = ph.v;
                *(short8*)&sS[((9 + k) * NT_ + wo) * 8] = pl.v;
            }
        }
        __syncthreads();

        const unsigned short* wc = wt3 + (size_t)(ch * NG) * O_ * 8;
#pragma unroll
        for (int ks = 0; ks < KSTEPS; ++ks) {
            int g  = ks * 4 + quad;
            int gb = (g < 18) ? g : ((g < 27) ? g - 18 : 18);   // t=2 reuses sh; 27 -> pad
            short8 afr[4];
#pragma unroll
            for (int ot = 0; ot < 4; ++ot)
                afr[ot] = *(const short8*)(wc + (size_t)(g * O_ + ot * 16 + l15) * 8);
            short8 bfr = *(const short8*)&sS[(gb * NT_ + wv * 16 + l15) * 8];
#pragma unroll
            for (int ot = 0; ot < 4; ++ot)
                acc[ot] = __builtin_amdgcn_mfma_f32_16x16x32_bf16(afr[ot], bfr, acc[ot], 0, 0, 0);
        }
        __syncthreads();
    }

    // ---- epilogue: C/D col = lane&15 (wo), row = quad*4+reg (o) ----
    const int wo = woB + wv * 16 + l15;
#pragma unroll
    for (int ot = 0; ot < 4; ++ot) {
#pragma unroll
        for (int rg = 0; rg < 4; ++rg) {
            int o = ot * 16 + quad * 4 + rg;
            out[(((size_t)(b * O_ + o)) * HO_ + ho) * WO_ + wo] = acc[ot][rg] + bias[o];
        }
    }
}

extern "C" void kernel_launch(void* const* d_in, const int* in_sizes, int n_in,
                              void* d_out, int out_size, void* d_ws, size_t ws_size,
                              hipStream_t stream) {
    const float* x    = (const float*)d_in[0];
    const float* off  = (const float*)d_in[1];
    const float* w    = (const float*)d_in[2];
    const float* bias = (const float*)d_in[3];
    float* out = (float*)d_out;

    unsigned short* wt3 = (unsigned short*)d_ws;            // 229376 B
    float* xt = (float*)((char*)d_ws + 262144);             // 16777216 B

    hipLaunchKernelGGL(wt3_prep, dim3((NCHUNK * NG * O_ + 255) / 256), dim3(256), 0, stream,
                       w, wt3);
    hipLaunchKernelGGL(x_nhwc, dim3(B_ * NCHUNK * H_ * W_ / 256), dim3(256), 0, stream,
                       x, xt);
    hipLaunchKernelGGL(dcn_mfma, dim3(B_ * HO_ * 2), dim3(256), 0, stream,
                       xt, off, wt3, bias, out);
}

// Round 5
// 135.556 us; speedup vs baseline: 1.7145x; 1.0585x over previous
//
#include <hip/hip_runtime.h>

// Deformable conv B=4 C=64 H=W=128 O=64 3x3 s1 p1 d1, DG=1.
// v5 = v4 hardened: 2-term bf16 (sh*wh + sh*wl), wave-specialized o-tiles,
// NT=32 / grid 2048, double-buffered LDS (16B-aligned), launch_bounds(256,4).

#define B_  4
#define C_  64
#define H_  128
#define W_  128
#define O_  64
#define HO_ 128
#define WO_ 128
#define NCH 8
#define NCHUNK 8
#define NG  20            // K-groups of 8 per chunk: 9 wh + 9 wl + 2 pad
#define KSTEPS 5          // NG*8 / 32
#define NT_ 32            // wo tile per block
#define NTASK (9 * NT_)   // 288 sampling tasks per chunk
#define SG  10            // sS groups per buffer: 9 sh + 1 zero pad
#define SBUF (SG * NT_ * 8)   // shorts per buffer (2560 = 5 KB)

typedef __attribute__((ext_vector_type(8))) short short8;
typedef __attribute__((ext_vector_type(4))) float f32x4;

__device__ __forceinline__ unsigned short f2bf(float f) {
    unsigned int u = __builtin_bit_cast(unsigned int, f);
    return (unsigned short)((u + 0x7FFFu + ((u >> 16) & 1u)) >> 16);
}
__device__ __forceinline__ float bf2f(unsigned short h) {
    unsigned int u = ((unsigned int)h) << 16;
    return __builtin_bit_cast(float, u);
}

// Merged prep: blocks [0,2048) transpose x -> xt [B][CH][H][W][8ch];
// blocks [2048,2088) build wt3[((ch*NG+g)*64+o)*8+e]: g<9 wh[k=g], 9..17 wl[k=g-9], 18/19 zero.
__global__ __launch_bounds__(256)
void prep(const float* __restrict__ x, const float* __restrict__ w,
          float* __restrict__ xt, unsigned short* __restrict__ wt3) {
    const int tid = threadIdx.x;
    if (blockIdx.x < 2048) {
        int t = blockIdx.x * 256 + tid;          // (b,ch,y,x)
        int xc = t & 127;
        int y  = (t >> 7) & 127;
        int ch = (t >> 14) & 7;
        int b  = t >> 17;
        const float* xp = x + (((size_t)(b * C_ + ch * NCH) * H_) + y) * W_ + xc;
        float4 v0, v1;
        v0.x = xp[0 * H_ * W_]; v0.y = xp[1 * H_ * W_];
        v0.z = xp[2 * H_ * W_]; v0.w = xp[3 * H_ * W_];
        v1.x = xp[4 * H_ * W_]; v1.y = xp[5 * H_ * W_];
        v1.z = xp[6 * H_ * W_]; v1.w = xp[7 * H_ * W_];
        float4* op = (float4*)(xt + (size_t)t * 8);
        op[0] = v0; op[1] = v1;
    } else {
        int t = (blockIdx.x - 2048) * 256 + tid;  // (ch,g,o), 10240 total
        if (t >= NCHUNK * NG * O_) return;
        int o  = t & 63;
        int g  = (t >> 6) % NG;
        int ch = (t >> 6) / NG;
        union { unsigned short u[8]; short8 v; } pk;
        if (g >= 18) {
#pragma unroll
            for (int e = 0; e < 8; ++e) pk.u[e] = 0;
        } else {
            int k = (g < 9) ? g : g - 9;
#pragma unroll
            for (int e = 0; e < 8; ++e) {
                float wf = w[(o * C_ + ch * NCH + e) * 9 + k];
                unsigned short wh = f2bf(wf);
                pk.u[e] = (g < 9) ? wh : f2bf(wf - bf2f(wh));
            }
        }
        *(short8*)(wt3 + (size_t)t * 8) = pk.v;
    }
}

__global__ __launch_bounds__(256, 4)
void dcn_mfma(const float* __restrict__ xt, const float* __restrict__ off,
              const unsigned short* __restrict__ wt3, const float* __restrict__ bias,
              float* __restrict__ out) {
    __shared__ __align__(16) unsigned short sS[2 * SBUF];   // 10 KB double-buffered

    const int tid = threadIdx.x;
    const int bid = blockIdx.x;              // (b, ho, wo-quarter)
    const int w4  = bid & 3;
    const int ho  = (bid >> 2) & (HO_ - 1);
    const int b   = bid >> 9;
    const int woB = w4 * NT_;

    // ---- bilinear metadata per (k, wo_local) task; x-select folded into weights ----
    int   a0_[2], a1_[2];
    float ua_[2], ub_[2], va_[2], vb_[2];
#pragma unroll
    for (int r = 0; r < 2; ++r) {
        int task = tid + r * 256;
        int tk = (task < NTASK) ? task : 0;
        int k  = tk >> 5;
        int wo = (tk & (NT_ - 1)) + woB;
        int ki = k / 3, kj = k - 3 * ki;
        float oy = off[(((b * 18) + 2 * k    ) * HO_ + ho) * WO_ + wo];
        float ox = off[(((b * 18) + 2 * k + 1) * HO_ + ho) * WO_ + wo];
        float py = (float)(ho - 1 + ki) + oy;
        float px = (float)(wo - 1 + kj) + ox;
        float y0f = floorf(py), x0f = floorf(px);
        int   y0 = (int)y0f,   x0 = (int)x0f;
        float ly = py - y0f,   lx = px - x0f;
        float hy = 1.f - ly,   hx = 1.f - lx;
        int y1 = y0 + 1, x1 = x0 + 1;
        float vy0 = (y0 >= 0 && y0 < H_) ? 1.f : 0.f;
        float vy1 = (y1 >= 0 && y1 < H_) ? 1.f : 0.f;
        float vx0 = (x0 >= 0 && x0 < W_) ? 1.f : 0.f;
        float vx1 = (x1 >= 0 && x1 < W_) ? 1.f : 0.f;
        int cy0 = min(max(y0, 0), H_ - 1), cy1 = min(max(y1, 0), H_ - 1);
        int cx0 = min(max(x0, 0), W_ - 1), cx1 = min(max(x1, 0), W_ - 1);
        int ax  = min(max(x0, 0), W_ - 2);
        float w00 = hy * hx * vy0 * vx0;
        float w01 = hy * lx * vy0 * vx1;
        float w10 = ly * hx * vy1 * vx0;
        float w11 = ly * lx * vy1 * vx1;
        float s0 = (cx0 != ax) ? 1.f : 0.f;
        float s1 = (cx1 != ax) ? 1.f : 0.f;
        a0_[r] = cy0 * W_ + ax;
        a1_[r] = cy1 * W_ + ax;
        ua_[r] = w00 * (1.f - s0) + w01 * (1.f - s1);
        ub_[r] = w00 * s0 + w01 * s1;
        va_[r] = w10 * (1.f - s0) + w11 * (1.f - s1);
        vb_[r] = w10 * s0 + w11 * s1;
    }

    // zero pad group (group 9) in both buffers: 128 dwords each
    if (tid < 128) {
        ((unsigned int*)&sS[9 * NT_ * 8])[tid]        = 0u;
        ((unsigned int*)&sS[SBUF + 9 * NT_ * 8])[tid] = 0u;
    }

    auto sample = [&](int ch, unsigned short* buf) {
        const float4* xc = (const float4*)(xt + ((size_t)(b * NCHUNK + ch)) * (H_ * W_ * 8));
#pragma unroll
        for (int r = 0; r < 2; ++r) {
            int task = tid + r * 256;
            if (task < NTASK) {
                int k  = task >> 5;
                int wo = task & (NT_ - 1);
                const int a0 = a0_[r] * 2, a1 = a1_[r] * 2;
                const float ua = ua_[r], ub = ub_[r], va = va_[r], vb = vb_[r];
                float4 p0 = xc[a0], p1 = xc[a0 + 1], p2 = xc[a0 + 2], p3 = xc[a0 + 3];
                float s[8];
                s[0] = ua * p0.x + ub * p2.x;  s[1] = ua * p0.y + ub * p2.y;
                s[2] = ua * p0.z + ub * p2.z;  s[3] = ua * p0.w + ub * p2.w;
                s[4] = ua * p1.x + ub * p3.x;  s[5] = ua * p1.y + ub * p3.y;
                s[6] = ua * p1.z + ub * p3.z;  s[7] = ua * p1.w + ub * p3.w;
                p0 = xc[a1]; p1 = xc[a1 + 1]; p2 = xc[a1 + 2]; p3 = xc[a1 + 3];
                s[0] += va * p0.x + vb * p2.x; s[1] += va * p0.y + vb * p2.y;
                s[2] += va * p0.z + vb * p2.z; s[3] += va * p0.w + vb * p2.w;
                s[4] += va * p1.x + vb * p3.x; s[5] += va * p1.y + vb * p3.y;
                s[6] += va * p1.z + vb * p3.z; s[7] += va * p1.w + vb * p3.w;
                union { unsigned short u[8]; short8 v; } ph;
#pragma unroll
                for (int e = 0; e < 8; ++e) ph.u[e] = f2bf(s[e]);
                *(short8*)&buf[(k * NT_ + wo) * 8] = ph.v;
            }
        }
    };

    const int lane = tid & 63;
    const int wv   = tid >> 6;        // wave -> o-tile of 16
    const int quad = lane >> 4;
    const int l15  = lane & 15;

    f32x4 acc[2];
    acc[0] = (f32x4){0.f, 0.f, 0.f, 0.f};
    acc[1] = (f32x4){0.f, 0.f, 0.f, 0.f};

    sample(0, sS);

    for (int ch = 0; ch < NCHUNK; ++ch) {
        __syncthreads();
        if (ch + 1 < NCHUNK) sample(ch + 1, sS + ((ch + 1) & 1) * SBUF);
        const unsigned short* buf = sS + (ch & 1) * SBUF;
        const unsigned short* wc  = wt3 + (size_t)(ch * NG) * O_ * 8;
#pragma unroll
        for (int ks = 0; ks < KSTEPS; ++ks) {
            int g  = ks * 4 + quad;
            int gb = (g < 9) ? g : ((g < 18) ? g - 9 : 9);   // wl pairs sh; 18/19 -> pad
            short8 afr = *(const short8*)(wc + (size_t)(g * O_ + wv * 16 + l15) * 8);
#pragma unroll
            for (int nt = 0; nt < 2; ++nt) {
                short8 bfr = *(const short8*)&buf[(gb * NT_ + nt * 16 + l15) * 8];
                acc[nt] = __builtin_amdgcn_mfma_f32_16x16x32_bf16(afr, bfr, acc[nt], 0, 0, 0);
            }
        }
    }

    // ---- epilogue: C/D col = lane&15 (wo), row = quad*4+reg (o within wave's 16) ----
#pragma unroll
    for (int nt = 0; nt < 2; ++nt) {
        int wo = woB + nt * 16 + l15;
#pragma unroll
        for (int rg = 0; rg < 4; ++rg) {
            int o = wv * 16 + quad * 4 + rg;
            out[(((size_t)(b * O_ + o)) * HO_ + ho) * WO_ + wo] = acc[nt][rg] + bias[o];
        }
    }
}

extern "C" void kernel_launch(void* const* d_in, const int* in_sizes, int n_in,
                              void* d_out, int out_size, void* d_ws, size_t ws_size,
                              hipStream_t stream) {
    const float* x    = (const float*)d_in[0];
    const float* off  = (const float*)d_in[1];
    const float* w    = (const float*)d_in[2];
    const float* bias = (const float*)d_in[3];
    float* out = (float*)d_out;

    unsigned short* wt3 = (unsigned short*)d_ws;            // 163840 B
    float* xt = (float*)((char*)d_ws + 262144);             // 16777216 B

    hipLaunchKernelGGL(prep, dim3(2048 + 40), dim3(256), 0, stream, x, w, xt, wt3);
    hipLaunchKernelGGL(dcn_mfma, dim3(B_ * HO_ * (WO_ / NT_)), dim3(256), 0, stream,
                       xt, off, wt3, bias, out);
}

// Round 6
// 116.536 us; speedup vs baseline: 1.9943x; 1.1632x over previous
//
#include <hip/hip_runtime.h>
#include <hip/hip_fp16.h>

// Deformable conv B=4 C=64 H=W=128 O=64 3x3 s1 p1 d1, DG=1.
// v6 = v5 + fp16 xt: one 16B gather per bilinear corner-row (halves TA requests,
// which R5 showed to be the roofline: ~1 divergent 16B req/cycle/CU).

#define B_  4
#define C_  64
#define H_  128
#define W_  128
#define O_  64
#define HO_ 128
#define WO_ 128
#define NCH 8
#define NCHUNK 8
#define NG  20            // K-groups of 8 per chunk: 9 wh + 9 wl + 2 pad
#define KSTEPS 5          // NG*8 / 32
#define NT_ 32            // wo tile per block
#define NTASK (9 * NT_)   // 288 sampling tasks per chunk
#define SG  10            // sS groups per buffer: 9 sh + 1 zero pad
#define SBUF (SG * NT_ * 8)   // shorts per buffer (2560 = 5 KB)

typedef __attribute__((ext_vector_type(8))) short short8;
typedef __attribute__((ext_vector_type(4))) float f32x4;

__device__ __forceinline__ unsigned short f2bf(float f) {
    unsigned int u = __builtin_bit_cast(unsigned int, f);
    return (unsigned short)((u + 0x7FFFu + ((u >> 16) & 1u)) >> 16);
}
__device__ __forceinline__ float bf2f(unsigned short h) {
    unsigned int u = ((unsigned int)h) << 16;
    return __builtin_bit_cast(float, u);
}

// Merged prep: blocks [0,2048) transpose+cvt x -> xt fp16 [B][CH=8][H][W][8ch];
// blocks [2048,2088) build wt3[((ch*NG+g)*64+o)*8+e]: g<9 wh[k=g], 9..17 wl[k=g-9], 18/19 zero.
__global__ __launch_bounds__(256)
void prep(const float* __restrict__ x, const float* __restrict__ w,
          __half* __restrict__ xt, unsigned short* __restrict__ wt3) {
    const int tid = threadIdx.x;
    if (blockIdx.x < 2048) {
        int t = blockIdx.x * 256 + tid;          // (b,ch,y,x)
        int xc = t & 127;
        int y  = (t >> 7) & 127;
        int ch = (t >> 14) & 7;
        int b  = t >> 17;
        const float* xp = x + (((size_t)(b * C_ + ch * NCH) * H_) + y) * W_ + xc;
        union { __half h[8]; float4 v; } pk;
#pragma unroll
        for (int e = 0; e < 8; ++e) pk.h[e] = __float2half_rn(xp[e * H_ * W_]);
        *(float4*)(xt + (size_t)t * 8) = pk.v;
    } else {
        int t = (blockIdx.x - 2048) * 256 + tid;  // (ch,g,o), 10240 total
        if (t >= NCHUNK * NG * O_) return;
        int o  = t & 63;
        int g  = (t >> 6) % NG;
        int ch = (t >> 6) / NG;
        union { unsigned short u[8]; short8 v; } pk;
        if (g >= 18) {
#pragma unroll
            for (int e = 0; e < 8; ++e) pk.u[e] = 0;
        } else {
            int k = (g < 9) ? g : g - 9;
#pragma unroll
            for (int e = 0; e < 8; ++e) {
                float wf = w[(o * C_ + ch * NCH + e) * 9 + k];
                unsigned short wh = f2bf(wf);
                pk.u[e] = (g < 9) ? wh : f2bf(wf - bf2f(wh));
            }
        }
        *(short8*)(wt3 + (size_t)t * 8) = pk.v;
    }
}

__global__ __launch_bounds__(256, 4)
void dcn_mfma(const __half* __restrict__ xt, const float* __restrict__ off,
              const unsigned short* __restrict__ wt3, const float* __restrict__ bias,
              float* __restrict__ out) {
    __shared__ __align__(16) unsigned short sS[2 * SBUF];   // 10 KB double-buffered

    const int tid = threadIdx.x;
    const int bid = blockIdx.x;              // (b, ho, wo-quarter)
    const int w4  = bid & 3;
    const int ho  = (bid >> 2) & (HO_ - 1);
    const int b   = bid >> 9;
    const int woB = w4 * NT_;

    // ---- bilinear metadata per (k, wo_local) task; x-select folded into weights ----
    int   a0_[2], a1_[2];
    float ua_[2], ub_[2], va_[2], vb_[2];
#pragma unroll
    for (int r = 0; r < 2; ++r) {
        int task = tid + r * 256;
        int tk = (task < NTASK) ? task : 0;
        int k  = tk >> 5;
        int wo = (tk & (NT_ - 1)) + woB;
        int ki = k / 3, kj = k - 3 * ki;
        float oy = off[(((b * 18) + 2 * k    ) * HO_ + ho) * WO_ + wo];
        float ox = off[(((b * 18) + 2 * k + 1) * HO_ + ho) * WO_ + wo];
        float py = (float)(ho - 1 + ki) + oy;
        float px = (float)(wo - 1 + kj) + ox;
        float y0f = floorf(py), x0f = floorf(px);
        int   y0 = (int)y0f,   x0 = (int)x0f;
        float ly = py - y0f,   lx = px - x0f;
        float hy = 1.f - ly,   hx = 1.f - lx;
        int y1 = y0 + 1, x1 = x0 + 1;
        float vy0 = (y0 >= 0 && y0 < H_) ? 1.f : 0.f;
        float vy1 = (y1 >= 0 && y1 < H_) ? 1.f : 0.f;
        float vx0 = (x0 >= 0 && x0 < W_) ? 1.f : 0.f;
        float vx1 = (x1 >= 0 && x1 < W_) ? 1.f : 0.f;
        int cy0 = min(max(y0, 0), H_ - 1), cy1 = min(max(y1, 0), H_ - 1);
        int cx0 = min(max(x0, 0), W_ - 1), cx1 = min(max(x1, 0), W_ - 1);
        int ax  = min(max(x0, 0), W_ - 2);
        float w00 = hy * hx * vy0 * vx0;
        float w01 = hy * lx * vy0 * vx1;
        float w10 = ly * hx * vy1 * vx0;
        float w11 = ly * lx * vy1 * vx1;
        float s0 = (cx0 != ax) ? 1.f : 0.f;
        float s1 = (cx1 != ax) ? 1.f : 0.f;
        a0_[r] = cy0 * W_ + ax;
        a1_[r] = cy1 * W_ + ax;
        ua_[r] = w00 * (1.f - s0) + w01 * (1.f - s1);
        ub_[r] = w00 * s0 + w01 * s1;
        va_[r] = w10 * (1.f - s0) + w11 * (1.f - s1);
        vb_[r] = w10 * s0 + w11 * s1;
    }

    // zero pad group (group 9) in both buffers: 128 dwords each
    if (tid < 128) {
        ((unsigned int*)&sS[9 * NT_ * 8])[tid]        = 0u;
        ((unsigned int*)&sS[SBUF + 9 * NT_ * 8])[tid] = 0u;
    }

    auto sample = [&](int ch, unsigned short* buf) {
        // fp16 plane: each (y,x) position = 8 halves = 16 B = one float4
        const float4* xc = (const float4*)(xt + ((size_t)(b * NCHUNK + ch)) * (H_ * W_ * 8));
#pragma unroll
        for (int r = 0; r < 2; ++r) {
            int task = tid + r * 256;
            if (task < NTASK) {
                int k  = task >> 5;
                int wo = task & (NT_ - 1);
                const int a0 = a0_[r], a1 = a1_[r];
                const float ua = ua_[r], ub = ub_[r], va = va_[r], vb = vb_[r];
                union H8 { float4 v; __half2 h2[4]; } q00, q01, q10, q11;
                q00.v = xc[a0];      // (y0, ax,   ch0..7)
                q01.v = xc[a0 + 1];  // (y0, ax+1, ch0..7)
                q10.v = xc[a1];      // (y1, ax,   ch0..7)
                q11.v = xc[a1 + 1];  // (y1, ax+1, ch0..7)
                union { unsigned short u[8]; short8 v; } ph;
#pragma unroll
                for (int j = 0; j < 4; ++j) {
                    float2 A0 = __half22float2(q00.h2[j]);
                    float2 B0 = __half22float2(q01.h2[j]);
                    float2 A1 = __half22float2(q10.h2[j]);
                    float2 B1 = __half22float2(q11.h2[j]);
                    float sx = ua * A0.x + ub * B0.x + va * A1.x + vb * B1.x;
                    float sy = ua * A0.y + ub * B0.y + va * A1.y + vb * B1.y;
                    ph.u[2 * j]     = f2bf(sx);
                    ph.u[2 * j + 1] = f2bf(sy);
                }
                *(short8*)&buf[(k * NT_ + wo) * 8] = ph.v;
            }
        }
    };

    const int lane = tid & 63;
    const int wv   = tid >> 6;        // wave -> o-tile of 16
    const int quad = lane >> 4;
    const int l15  = lane & 15;

    f32x4 acc[2];
    acc[0] = (f32x4){0.f, 0.f, 0.f, 0.f};
    acc[1] = (f32x4){0.f, 0.f, 0.f, 0.f};

    sample(0, sS);

    for (int ch = 0; ch < NCHUNK; ++ch) {
        __syncthreads();
        if (ch + 1 < NCHUNK) sample(ch + 1, sS + ((ch + 1) & 1) * SBUF);
        const unsigned short* buf = sS + (ch & 1) * SBUF;
        const unsigned short* wc  = wt3 + (size_t)(ch * NG) * O_ * 8;
#pragma unroll
        for (int ks = 0; ks < KSTEPS; ++ks) {
            int g  = ks * 4 + quad;
            int gb = (g < 9) ? g : ((g < 18) ? g - 9 : 9);   // wl pairs sh; 18/19 -> pad
            short8 afr = *(const short8*)(wc + (size_t)(g * O_ + wv * 16 + l15) * 8);
#pragma unroll
            for (int nt = 0; nt < 2; ++nt) {
                short8 bfr = *(const short8*)&buf[(gb * NT_ + nt * 16 + l15) * 8];
                acc[nt] = __builtin_amdgcn_mfma_f32_16x16x32_bf16(afr, bfr, acc[nt], 0, 0, 0);
            }
        }
    }

    // ---- epilogue: C/D col = lane&15 (wo), row = quad*4+reg (o within wave's 16) ----
#pragma unroll
    for (int nt = 0; nt < 2; ++nt) {
        int wo = woB + nt * 16 + l15;
#pragma unroll
        for (int rg = 0; rg < 4; ++rg) {
            int o = wv * 16 + quad * 4 + rg;
            out[(((size_t)(b * O_ + o)) * HO_ + ho) * WO_ + wo] = acc[nt][rg] + bias[o];
        }
    }
}

extern "C" void kernel_launch(void* const* d_in, const int* in_sizes, int n_in,
                              void* d_out, int out_size, void* d_ws, size_t ws_size,
                              hipStream_t stream) {
    const float* x    = (const float*)d_in[0];
    const float* off  = (const float*)d_in[1];
    const float* w    = (const float*)d_in[2];
    const float* bias = (const float*)d_in[3];
    float* out = (float*)d_out;

    unsigned short* wt3 = (unsigned short*)d_ws;            // 163840 B
    __half* xt = (__half*)((char*)d_ws + 262144);           // 4*8*128*128*8 halves = 8 MB

    hipLaunchKernelGGL(prep, dim3(2048 + 40), dim3(256), 0, stream, x, w, xt, wt3);
    hipLaunchKernelGGL(dcn_mfma, dim3(B_ * HO_ * (WO_ / NT_)), dim3(256), 0, stream,
                       xt, off, wt3, bias, out);
}

// Round 7
// 107.154 us; speedup vs baseline: 2.1689x; 1.0876x over previous
//
#include <hip/hip_runtime.h>
#include <hip/hip_fp16.h>

// Deformable conv B=4 C=64 H=W=128 O=64 3x3 s1 p1 d1, DG=1.
// v7: single-term fp16 MFMA GEMM (fp16 11-bit mantissa makes hi/lo split
// unnecessary), packed-fp16 blend, gather prefetch across the MFMA loop
// (hides TA latency behind compute), 2x2 wave split (halves B LDS reads).

#define B_  4
#define C_  64
#define H_  128
#define W_  128
#define O_  64
#define HO_ 128
#define WO_ 128
#define NCHUNK 8
#define NGW 12            // weight K-groups per chunk: 9 real taps + 3 zero
#define KSTEPS 3          // NGW*8 / 32
#define NT_ 32            // wo tile per block
#define NTASK (9 * NT_)   // 288 sampling tasks per chunk
#define SG  10            // sS groups per buffer: 9 taps + 1 zero pad
#define SBUF (SG * NT_ * 8)   // halves per buffer (2560 = 5 KB)

typedef _Float16 half8 __attribute__((ext_vector_type(8)));
typedef __attribute__((ext_vector_type(4))) float f32x4;

union H8 { float4 v; __half2 h2[4]; half8 v8; };

// Merged prep: blocks [0,2048) transpose+cvt x -> xt fp16 [B][CH=8][H][W][8ch];
// blocks [2048,2072) build wt fp16 [(ch*12+g)*64+o]*8+e  (g<9: tap g, else 0).
__global__ __launch_bounds__(256)
void prep(const float* __restrict__ x, const float* __restrict__ w,
          __half* __restrict__ xt, __half* __restrict__ wt) {
    const int tid = threadIdx.x;
    if (blockIdx.x < 2048) {
        int t = blockIdx.x * 256 + tid;          // (b,ch,y,x)
        int xc = t & 127;
        int y  = (t >> 7) & 127;
        int ch = (t >> 14) & 7;
        int b  = t >> 17;
        const float* xp = x + (((size_t)(b * C_ + ch * 8) * H_) + y) * W_ + xc;
        union { __half h[8]; float4 v; } pk;
#pragma unroll
        for (int e = 0; e < 8; ++e) pk.h[e] = __float2half_rn(xp[e * H_ * W_]);
        *(float4*)(xt + (size_t)t * 8) = pk.v;
    } else {
        int t = (blockIdx.x - 2048) * 256 + tid;  // (ch,g,o), 6144 total
        if (t >= NCHUNK * NGW * O_) return;
        int o  = t & 63;
        int g  = (t >> 6) % NGW;
        int ch = (t >> 6) / NGW;
        union { __half h[8]; float4 v; } pk;
#pragma unroll
        for (int e = 0; e < 8; ++e)
            pk.h[e] = (g < 9) ? __float2half_rn(w[(o * C_ + ch * 8 + e) * 9 + g])
                              : __half(0.0f);
        *(float4*)(wt + (size_t)t * 8) = pk.v;
    }
}

__global__ __launch_bounds__(256, 4)
void dcn_mfma(const __half* __restrict__ xt, const float* __restrict__ off,
              const __half* __restrict__ wt, const float* __restrict__ bias,
              float* __restrict__ out) {
    __shared__ __align__(16) _Float16 sS[2 * SBUF];   // 10 KB double-buffered

    const int tid = threadIdx.x;
    const int bid = blockIdx.x;              // (b, ho, wo-quarter)
    const int w4  = bid & 3;
    const int ho  = (bid >> 2) & (HO_ - 1);
    const int b   = bid >> 9;
    const int woB = w4 * NT_;

    // ---- bilinear metadata per (k, wo_local) task; x-select folded into
    // corner weights, weights pre-packed to __half2 ----
    int a0_[2], a1_[2];
    __half2 ua2_[2], ub2_[2], va2_[2], vb2_[2];
#pragma unroll
    for (int r = 0; r < 2; ++r) {
        int task = tid + r * 256;
        int tk = (task < NTASK) ? task : 0;
        int k  = tk >> 5;
        int wo = (tk & (NT_ - 1)) + woB;
        int ki = k / 3, kj = k - 3 * ki;
        float oy = off[(((b * 18) + 2 * k    ) * HO_ + ho) * WO_ + wo];
        float ox = off[(((b * 18) + 2 * k + 1) * HO_ + ho) * WO_ + wo];
        float py = (float)(ho - 1 + ki) + oy;
        float px = (float)(wo - 1 + kj) + ox;
        float y0f = floorf(py), x0f = floorf(px);
        int   y0 = (int)y0f,   x0 = (int)x0f;
        float ly = py - y0f,   lx = px - x0f;
        float hy = 1.f - ly,   hx = 1.f - lx;
        int y1 = y0 + 1, x1 = x0 + 1;
        float vy0 = (y0 >= 0 && y0 < H_) ? 1.f : 0.f;
        float vy1 = (y1 >= 0 && y1 < H_) ? 1.f : 0.f;
        float vx0 = (x0 >= 0 && x0 < W_) ? 1.f : 0.f;
        float vx1 = (x1 >= 0 && x1 < W_) ? 1.f : 0.f;
        int cy0 = min(max(y0, 0), H_ - 1), cy1 = min(max(y1, 0), H_ - 1);
        int cx0 = min(max(x0, 0), W_ - 1), cx1 = min(max(x1, 0), W_ - 1);
        int ax  = min(max(x0, 0), W_ - 2);
        float w00 = hy * hx * vy0 * vx0;
        float w01 = hy * lx * vy0 * vx1;
        float w10 = ly * hx * vy1 * vx0;
        float w11 = ly * lx * vy1 * vx1;
        float s0 = (cx0 != ax) ? 1.f : 0.f;
        float s1 = (cx1 != ax) ? 1.f : 0.f;
        a0_[r] = cy0 * W_ + ax;
        a1_[r] = cy1 * W_ + ax;
        ua2_[r] = __float2half2_rn(w00 * (1.f - s0) + w01 * (1.f - s1));
        ub2_[r] = __float2half2_rn(w00 * s0 + w01 * s1);
        va2_[r] = __float2half2_rn(w10 * (1.f - s0) + w11 * (1.f - s1));
        vb2_[r] = __float2half2_rn(w10 * s0 + w11 * s1);
    }

    // zero pad group (group 9) in both buffers: 128 dwords each
    if (tid < 128) {
        ((unsigned int*)&sS[9 * NT_ * 8])[tid]        = 0u;
        ((unsigned int*)&sS[SBUF + 9 * NT_ * 8])[tid] = 0u;
    }

    // ---- gather prefetch registers (chunk-ahead) ----
    H8 q00, q01, q10, q11;      // r=0 task (all 256 threads)
    H8 p00, p01, p10, p11;      // r=1 task (tid < 32 only)

    auto issue = [&](int ch) {
        const float4* xc = (const float4*)(xt + ((size_t)(b * NCHUNK + ch)) * (H_ * W_ * 8));
        q00.v = xc[a0_[0]];      q01.v = xc[a0_[0] + 1];
        q10.v = xc[a1_[0]];      q11.v = xc[a1_[0] + 1];
        if (tid < 32) {
            p00.v = xc[a0_[1]];  p01.v = xc[a0_[1] + 1];
            p10.v = xc[a1_[1]];  p11.v = xc[a1_[1] + 1];
        }
    };

    auto blend = [&](int bufi) {
        _Float16* buf = sS + bufi * SBUF;
        {
            int k = tid >> 5, wo = tid & (NT_ - 1);
            H8 s;
#pragma unroll
            for (int j = 0; j < 4; ++j) {
                __half2 t0 = __hmul2(ua2_[0], q00.h2[j]);
                t0 = __hfma2(ub2_[0], q01.h2[j], t0);
                t0 = __hfma2(va2_[0], q10.h2[j], t0);
                t0 = __hfma2(vb2_[0], q11.h2[j], t0);
                s.h2[j] = t0;
            }
            *(half8*)&buf[(k * NT_ + wo) * 8] = s.v8;
        }
        if (tid < 32) {
            int task = tid + 256;
            int k = task >> 5, wo = task & (NT_ - 1);
            H8 s;
#pragma unroll
            for (int j = 0; j < 4; ++j) {
                __half2 t0 = __hmul2(ua2_[1], p00.h2[j]);
                t0 = __hfma2(ub2_[1], p01.h2[j], t0);
                t0 = __hfma2(va2_[1], p10.h2[j], t0);
                t0 = __hfma2(vb2_[1], p11.h2[j], t0);
                s.h2[j] = t0;
            }
            *(half8*)&buf[(k * NT_ + wo) * 8] = s.v8;
        }
    };

    // ---- GEMM lane mapping: 2x2 wave split (ow: o-half of 32, nw: wo-half of 16) ----
    const int lane = tid & 63;
    const int wv   = tid >> 6;
    const int ow   = wv & 1;
    const int nw   = wv >> 1;
    const int quad = lane >> 4;
    const int l15  = lane & 15;

    f32x4 acc[2];
    acc[0] = (f32x4){0.f, 0.f, 0.f, 0.f};
    acc[1] = (f32x4){0.f, 0.f, 0.f, 0.f};

    issue(0);

    for (int ch = 0; ch < NCHUNK; ++ch) {
        blend(ch & 1);
        __syncthreads();
        if (ch + 1 < NCHUNK) issue(ch + 1);   // latency hidden behind MFMA below

        const __half*   wc  = wt + (size_t)(ch * NGW) * O_ * 8;
        const _Float16* buf = sS + (ch & 1) * SBUF;
#pragma unroll
        for (int ks = 0; ks < KSTEPS; ++ks) {
            int g  = ks * 4 + quad;
            int gb = (g < 9) ? g : 9;            // groups 9..11 -> zero pad
            half8 bfr = *(const half8*)&buf[(gb * NT_ + nw * 16 + l15) * 8];
#pragma unroll
            for (int ot = 0; ot < 2; ++ot) {
                half8 afr = *(const half8*)(wc + (size_t)(g * O_ + ow * 32 + ot * 16 + l15) * 8);
                acc[ot] = __builtin_amdgcn_mfma_f32_16x16x32_f16(afr, bfr, acc[ot], 0, 0, 0);
            }
        }
        // single barrier per chunk: next iteration's blend writes the OTHER
        // buffer; writes to THIS buffer (ch+2) only happen after the next
        // barrier, which orders them after every wave's MFMA reads above.
    }

    // ---- epilogue: C/D col = lane&15 (wo), row = quad*4+reg (o) ----
#pragma unroll
    for (int ot = 0; ot < 2; ++ot) {
        int wo = woB + nw * 16 + l15;
#pragma unroll
        for (int rg = 0; rg < 4; ++rg) {
            int o = ow * 32 + ot * 16 + quad * 4 + rg;
            out[(((size_t)(b * O_ + o)) * HO_ + ho) * WO_ + wo] = acc[ot][rg] + bias[o];
        }
    }
}

extern "C" void kernel_launch(void* const* d_in, const int* in_sizes, int n_in,
                              void* d_out, int out_size, void* d_ws, size_t ws_size,
                              hipStream_t stream) {
    const float* x    = (const float*)d_in[0];
    const float* off  = (const float*)d_in[1];
    const float* w    = (const float*)d_in[2];
    const float* bias = (const float*)d_in[3];
    float* out = (float*)d_out;

    __half* wt = (__half*)d_ws;                       // 8*12*64*8*2 = 98304 B
    __half* xt = (__half*)((char*)d_ws + 262144);     // 8 MB

    hipLaunchKernelGGL(prep, dim3(2048 + 24), dim3(256), 0, stream, x, w, xt, wt);
    hipLaunchKernelGGL(dcn_mfma, dim3(B_ * HO_ * (WO_ / NT_)), dim3(256), 0, stream,
                       xt, off, wt, bias, out);
}

// Round 8
// 101.081 us; speedup vs baseline: 2.2992x; 1.0601x over previous
//
#include <hip/hip_runtime.h>
#include <hip/hip_fp16.h>

// Deformable conv B=4 C=64 H=W=128 O=64 3x3 s1 p1 d1, DG=1.
// v8 = v7 + LDS-window gather: per chunk, stage a 16x48 fp16-octet window of x
// around (ho, woB) into LDS with coalesced loads, bilinear-gather from LDS
// (ds_read_b128) instead of divergent global loads (R5-R7 showed the TA
// divergent-request rate ~1 16B-seg/cy/CU is the roofline). Out-of-window
// taps (|offset|>~6, p~1e-9/sample) take an exact global fallback.

#define B_  4
#define C_  64
#define H_  128
#define W_  128
#define O_  64
#define HO_ 128
#define WO_ 128
#define NCHUNK 8
#define NGW 12            // weight K-groups per chunk: 9 real taps + 3 zero
#define KSTEPS 3          // NGW*8 / 32
#define NT_ 32            // wo tile per block
#define NTASK (9 * NT_)   // 288 sampling tasks per chunk
#define SG  10            // sS groups per buffer: 9 taps + 1 zero pad
#define SBUF (SG * NT_ * 8)   // halves per buffer (2560 = 5 KB)
#define TR  16            // tile rows    (y in [ho-7, ho+9))
#define TC  48            // tile cols    (x in [woB-8, woB+40))
#define TSLOTS (TR * TC)  // 768 positions x 16 B = 12 KB

typedef _Float16 half8 __attribute__((ext_vector_type(8)));
typedef __attribute__((ext_vector_type(4))) float f32x4;

union H8 { float4 v; __half2 h2[4]; half8 v8; };

// Merged prep: blocks [0,2048) transpose+cvt x -> xt fp16 [B][CH=8][H][W][8ch];
// blocks [2048,2072) build wt fp16 [(ch*12+g)*64+o]*8+e  (g<9: tap g, else 0).
__global__ __launch_bounds__(256)
void prep(const float* __restrict__ x, const float* __restrict__ w,
          __half* __restrict__ xt, __half* __restrict__ wt) {
    const int tid = threadIdx.x;
    if (blockIdx.x < 2048) {
        int t = blockIdx.x * 256 + tid;          // (b,ch,y,x)
        int xc = t & 127;
        int y  = (t >> 7) & 127;
        int ch = (t >> 14) & 7;
        int b  = t >> 17;
        const float* xp = x + (((size_t)(b * C_ + ch * 8) * H_) + y) * W_ + xc;
        union { __half h[8]; float4 v; } pk;
#pragma unroll
        for (int e = 0; e < 8; ++e) pk.h[e] = __float2half_rn(xp[e * H_ * W_]);
        *(float4*)(xt + (size_t)t * 8) = pk.v;
    } else {
        int t = (blockIdx.x - 2048) * 256 + tid;  // (ch,g,o), 6144 total
        if (t >= NCHUNK * NGW * O_) return;
        int o  = t & 63;
        int g  = (t >> 6) % NGW;
        int ch = (t >> 6) / NGW;
        union { __half h[8]; float4 v; } pk;
#pragma unroll
        for (int e = 0; e < 8; ++e)
            pk.h[e] = (g < 9) ? __float2half_rn(w[(o * C_ + ch * 8 + e) * 9 + g])
                              : __half(0.0f);
        *(float4*)(wt + (size_t)t * 8) = pk.v;
    }
}

__global__ __launch_bounds__(256, 4)
void dcn_mfma(const __half* __restrict__ xt, const float* __restrict__ off,
              const __half* __restrict__ wt, const float* __restrict__ bias,
              float* __restrict__ out) {
    __shared__ __align__(16) _Float16 sS[2 * SBUF];   // 10 KB double-buffered
    __shared__ __align__(16) _Float16 sT[TSLOTS * 8]; // 12 KB x-window tile

    const int tid = threadIdx.x;
    const int bid = blockIdx.x;              // (b, ho, wo-quarter)
    const int w4  = bid & 3;
    const int ho  = (bid >> 2) & (HO_ - 1);
    const int b   = bid >> 9;
    const int woB = w4 * NT_;
    const int yb  = ho - 7;                  // tile origin (row)
    const int xb  = woB - 8;                 // tile origin (col)

    // ---- bilinear metadata per (k, wo_local) task: tile-local coords + fallback ----
    int ty0_[2], ty1_[2], tx_[2], fb_[2];
    __half2 ua2_[2], ub2_[2], va2_[2], vb2_[2];
#pragma unroll
    for (int r = 0; r < 2; ++r) {
        int task = tid + r * 256;
        int tk = (task < NTASK) ? task : 0;
        int k  = tk >> 5;
        int wo = (tk & (NT_ - 1)) + woB;
        int ki = k / 3, kj = k - 3 * ki;
        float oy = off[(((b * 18) + 2 * k    ) * HO_ + ho) * WO_ + wo];
        float ox = off[(((b * 18) + 2 * k + 1) * HO_ + ho) * WO_ + wo];
        float py = (float)(ho - 1 + ki) + oy;
        float px = (float)(wo - 1 + kj) + ox;
        float y0f = floorf(py), x0f = floorf(px);
        int   y0 = (int)y0f,   x0 = (int)x0f;
        float ly = py - y0f,   lx = px - x0f;
        float hy = 1.f - ly,   hx = 1.f - lx;
        int y1 = y0 + 1, x1 = x0 + 1;
        float vy0 = (y0 >= 0 && y0 < H_) ? 1.f : 0.f;
        float vy1 = (y1 >= 0 && y1 < H_) ? 1.f : 0.f;
        float vx0 = (x0 >= 0 && x0 < W_) ? 1.f : 0.f;
        float vx1 = (x1 >= 0 && x1 < W_) ? 1.f : 0.f;
        int cy0 = min(max(y0, 0), H_ - 1), cy1 = min(max(y1, 0), H_ - 1);
        int cx0 = min(max(x0, 0), W_ - 1), cx1 = min(max(x1, 0), W_ - 1);
        int ax  = min(max(x0, 0), W_ - 2);
        float w00 = hy * hx * vy0 * vx0;
        float w01 = hy * lx * vy0 * vx1;
        float w10 = ly * hx * vy1 * vx0;
        float w11 = ly * lx * vy1 * vx1;
        float s0 = (cx0 != ax) ? 1.f : 0.f;
        float s1 = (cx1 != ax) ? 1.f : 0.f;
        ty0_[r] = cy0 - yb;
        ty1_[r] = cy1 - yb;
        tx_[r]  = ax - xb;
        fb_[r]  = ((unsigned)ty0_[r] > (unsigned)(TR - 1)) |
                  ((unsigned)ty1_[r] > (unsigned)(TR - 1)) |
                  ((unsigned)tx_[r]  > (unsigned)(TC - 2));
        ua2_[r] = __float2half2_rn(w00 * (1.f - s0) + w01 * (1.f - s1));
        ub2_[r] = __float2half2_rn(w00 * s0 + w01 * s1);
        va2_[r] = __float2half2_rn(w10 * (1.f - s0) + w11 * (1.f - s1));
        vb2_[r] = __float2half2_rn(w10 * s0 + w11 * s1);
    }

    // ---- stage-slot global offsets (clamped), 3 slots/thread ----
    int gofs[3];
#pragma unroll
    for (int j = 0; j < 3; ++j) {
        int s  = tid + j * 256;
        int rr = s / TC, cc = s - rr * TC;
        int yc = min(max(yb + rr, 0), H_ - 1);
        int xc = min(max(xb + cc, 0), W_ - 1);
        gofs[j] = yc * W_ + xc;
    }

    // zero pad group (group 9) in both sS buffers: 128 dwords each
    if (tid < 128) {
        ((unsigned int*)&sS[9 * NT_ * 8])[tid]        = 0u;
        ((unsigned int*)&sS[SBUF + 9 * NT_ * 8])[tid] = 0u;
    }

    // ---- window prefetch registers ----
    float4 pf0, pf1, pf2;
    auto issue = [&](int ch) {
        const float4* xc = (const float4*)(xt + ((size_t)(b * NCHUNK + ch)) * (H_ * W_ * 8));
        pf0 = xc[gofs[0]];
        pf1 = xc[gofs[1]];
        pf2 = xc[gofs[2]];
    };

    // ---- sample: LDS-window bilinear gather + fp16 blend -> sS[parity] ----
    auto sample = [&](int ch) {
        _Float16* buf = sS + (ch & 1) * SBUF;
        const float4* xcg = (const float4*)(xt + ((size_t)(b * NCHUNK + ch)) * (H_ * W_ * 8));
        const float4* tl  = (const float4*)sT;
#pragma unroll
        for (int r = 0; r < 2; ++r) {
            int task = tid + r * 256;
            if (task < NTASK) {
                int k  = task >> 5;
                int wo = task & (NT_ - 1);
                H8 q00, q01, q10, q11;
                if (!fb_[r]) {
                    int a0 = ty0_[r] * TC + tx_[r];
                    int a1 = ty1_[r] * TC + tx_[r];
                    q00.v = tl[a0];  q01.v = tl[a0 + 1];
                    q10.v = tl[a1];  q11.v = tl[a1 + 1];
                } else {   // exact fallback for |offset| beyond the window (~never)
                    int a0 = (ty0_[r] + yb) * W_ + (tx_[r] + xb);
                    int a1 = (ty1_[r] + yb) * W_ + (tx_[r] + xb);
                    q00.v = xcg[a0]; q01.v = xcg[a0 + 1];
                    q10.v = xcg[a1]; q11.v = xcg[a1 + 1];
                }
                H8 s;
#pragma unroll
                for (int j = 0; j < 4; ++j) {
                    __half2 t0 = __hmul2(ua2_[r], q00.h2[j]);
                    t0 = __hfma2(ub2_[r], q01.h2[j], t0);
                    t0 = __hfma2(va2_[r], q10.h2[j], t0);
                    t0 = __hfma2(vb2_[r], q11.h2[j], t0);
                    s.h2[j] = t0;
                }
                *(half8*)&buf[(k * NT_ + wo) * 8] = s.v8;
            }
        }
    };

    // ---- GEMM lane mapping: 2x2 wave split ----
    const int lane = tid & 63;
    const int wv   = tid >> 6;
    const int ow   = wv & 1;
    const int nw   = wv >> 1;
    const int quad = lane >> 4;
    const int l15  = lane & 15;

    f32x4 acc[2];
    acc[0] = (f32x4){0.f, 0.f, 0.f, 0.f};
    acc[1] = (f32x4){0.f, 0.f, 0.f, 0.f};

    auto mfma_chunk = [&](int ch) {
        const __half*   wc  = wt + (size_t)(ch * NGW) * O_ * 8;
        const _Float16* buf = sS + (ch & 1) * SBUF;
#pragma unroll
        for (int ks = 0; ks < KSTEPS; ++ks) {
            int g  = ks * 4 + quad;
            int gb = (g < 9) ? g : 9;            // groups 9..11 -> zero pad
            half8 bfr = *(const half8*)&buf[(gb * NT_ + nw * 16 + l15) * 8];
#pragma unroll
            for (int ot = 0; ot < 2; ++ot) {
                half8 afr = *(const half8*)(wc + (size_t)(g * O_ + ow * 32 + ot * 16 + l15) * 8);
                acc[ot] = __builtin_amdgcn_mfma_f32_16x16x32_f16(afr, bfr, acc[ot], 0, 0, 0);
            }
        }
    };

    issue(0);
    for (int ch = 0; ch < NCHUNK; ++ch) {
        // write the x-window tile (waits on the prefetch issued last chunk)
        float4* tw = (float4*)sT;
        tw[tid]       = pf0;
        tw[tid + 256] = pf1;
        tw[tid + 512] = pf2;
        __syncthreads();                       // tile ready; sS[(ch-1)&1] complete
        if (ch + 1 < NCHUNK) issue(ch + 1);    // overlap next window fetch with compute
        sample(ch);                            // LDS gather -> sS[ch&1]
        if (ch > 0) mfma_chunk(ch - 1);        // reads sS[(ch-1)&1], other parity
        __syncthreads();                       // sample done: tile free, sS[ch&1] ready
    }
    mfma_chunk(NCHUNK - 1);

    // ---- epilogue: C/D col = lane&15 (wo), row = quad*4+reg (o) ----
#pragma unroll
    for (int ot = 0; ot < 2; ++ot) {
        int wo = woB + nw * 16 + l15;
#pragma unroll
        for (int rg = 0; rg < 4; ++rg) {
            int o = ow * 32 + ot * 16 + quad * 4 + rg;
            out[(((size_t)(b * O_ + o)) * HO_ + ho) * WO_ + wo] = acc[ot][rg] + bias[o];
        }
    }
}

extern "C" void kernel_launch(void* const* d_in, const int* in_sizes, int n_in,
                              void* d_out, int out_size, void* d_ws, size_t ws_size,
                              hipStream_t stream) {
    const float* x    = (const float*)d_in[0];
    const float* off  = (const float*)d_in[1];
    const float* w    = (const float*)d_in[2];
    const float* bias = (const float*)d_in[3];
    float* out = (float*)d_out;

    __half* wt = (__half*)d_ws;                       // 98304 B
    __half* xt = (__half*)((char*)d_ws + 262144);     // 8 MB

    hipLaunchKernelGGL(prep, dim3(2048 + 24), dim3(256), 0, stream, x, w, xt, wt);
    hipLaunchKernelGGL(dcn_mfma, dim3(B_ * HO_ * (WO_ / NT_)), dim3(256), 0, stream,
                       xt, off, wt, bias, out);
}